// Round 3
// baseline (206.080 us; speedup 1.0000x reference)
//
#include <hip/hip_runtime.h>
#include <stdint.h>

#define BB 16
#define NN 1024
#define DD 64
#define CC 64
#define KMAX 20
#define ROWS 8

// ---------------- K0: counts + k_eff (one block) ----------------
__global__ void k0_counts(const void* __restrict__ maskp,
                          int* __restrict__ counts, int* __restrict__ keff) {
    __shared__ int scnt[BB];
    int tid = threadIdx.x;
    int w = tid >> 6, lane = tid & 63;
    const unsigned char* mb = (const unsigned char*)maskp;
    const int* mi = (const int*)maskp;
    bool bytelayout = (mb[1] != 0);
    int s = 0;
    for (int i = 0; i < 16; ++i) {
        int n = lane + (i << 6);
        int v = bytelayout ? (mb[w * NN + n] ? 1 : 0) : (mi[w * NN + n] ? 1 : 0);
        s += v;
    }
    for (int off = 32; off; off >>= 1) s += __shfl_xor(s, off);
    if (lane == 0) scnt[w] = s;
    __syncthreads();
    if (tid < BB) {
        int minc = scnt[0];
        for (int q = 1; q < BB; ++q) minc = min(minc, scnt[q]);
        int kglob = min(KMAX, max(1, minc - 1));
        float c = (float)scnt[tid];
        float v = sqrtf(c / 50.0f) * 8.0f;
        v = fminf(fmaxf(v, 8.0f), 20.0f);
        int kper = (int)v;
        counts[tid] = scnt[tid];
        keff[tid] = min(kper, kglob);
    }
}

// ---------------- K1: base/fb feats + x2 + transpose x -> xT[b][d][n] ----------------
__global__ void k1_feats(const float* __restrict__ x, const float* __restrict__ W1,
                         const float* __restrict__ b1, float* __restrict__ base,
                         float* __restrict__ fb, float* __restrict__ x2,
                         float* __restrict__ xT) {
    __shared__ float sXT[DD][4];
    int w = threadIdx.x >> 6, lane = threadIdx.x & 63;
    int p = blockIdx.x * 4 + w;
    const float* xp = x + (size_t)p * DD;
    float xv = xp[lane];
    float sq = xv * xv;
    for (int off = 32; off; off >>= 1) sq += __shfl_xor(sq, off);
    if (lane == 0) x2[p] = sq;
    sXT[lane][w] = xv;
    float acc_a = 0.f, acc_b = 0.f;
#pragma unroll
    for (int d = 0; d < DD; ++d) {
        float xd = __shfl(xv, d);  // == xp[d], bit-identical
        acc_a = fmaf(xd, W1[d * CC + lane], acc_a);
        acc_b = fmaf(xd, W1[(DD + d) * CC + lane], acc_b);
    }
    base[(size_t)p * CC + lane] = acc_a - acc_b + b1[lane];
    fb[(size_t)p * CC + lane] = acc_b;
    __syncthreads();
    int t = threadIdx.x;
    int d = t >> 2, po = t & 3;
    int p0 = blockIdx.x * 4;
    int b = p0 >> 10, nb = p0 & 1023;
    xT[(((size_t)(b << 6) + d) << 10) + nb + po] = sXT[d][po];
}

// Batcher odd-even mergesort compare-exchange (ascending)
#define CE(a, b)                                                      \
    {                                                                 \
        bool sw_ = packed[b] < packed[a];                             \
        unsigned long long ta_ = packed[a];                           \
        packed[a] = sw_ ? packed[b] : packed[a];                      \
        packed[b] = sw_ ? ta_ : packed[b];                            \
    }

// ---------------- K2: GEMM-style dist + presort-pop top-k ----------------
__global__ __launch_bounds__(256) void k2_knn(const float* __restrict__ x,
                                              const float* __restrict__ xT,
                                              const float* __restrict__ x2,
                                              const int* __restrict__ counts,
                                              const int* __restrict__ keff,
                                              int* __restrict__ idx) {
    __shared__ float sD[ROWS][NN];
    __shared__ float sRow[ROWS][DD];
    __shared__ float sX2[NN];
    int b = blockIdx.x >> 7;
    int n0 = (blockIdx.x & 127) * ROWS;
    int w = threadIdx.x >> 6, lane = threadIdx.x & 63;
    int cnt = counts[b], kef = keff[b];
    int t = threadIdx.x;
    if (t < ROWS * 16) {
        int r = t >> 4, dc = (t & 15) << 2;
        *(float4*)&sRow[r][dc] =
            *(const float4*)(x + ((size_t)(b << 10) + n0 + r) * DD + dc);
    }
    *(float4*)&sX2[t << 2] = *(const float4*)(x2 + (b << 10) + (t << 2));
    __syncthreads();

    // GEMM phase: wave w covers candidates c0 = w*256 + lane*4 .. +3, all 8 rows
    float4 acc[ROWS];
#pragma unroll
    for (int r = 0; r < ROWS; ++r) acc[r] = make_float4(0.f, 0.f, 0.f, 0.f);
    const float* xTb = xT + ((size_t)b << 16);
    int c0 = (w << 8) + (lane << 2);
    for (int d0 = 0; d0 < DD; d0 += 4) {
        float4 cv0 = *(const float4*)(xTb + ((size_t)(d0 + 0) << 10) + c0);
        float4 cv1 = *(const float4*)(xTb + ((size_t)(d0 + 1) << 10) + c0);
        float4 cv2 = *(const float4*)(xTb + ((size_t)(d0 + 2) << 10) + c0);
        float4 cv3 = *(const float4*)(xTb + ((size_t)(d0 + 3) << 10) + c0);
#pragma unroll
        for (int r = 0; r < ROWS; ++r) {
            float4 rv = *(const float4*)(&sRow[r][d0]);   // wave-uniform broadcast
            acc[r].x = fmaf(rv.x, cv0.x, acc[r].x);
            acc[r].y = fmaf(rv.x, cv0.y, acc[r].y);
            acc[r].z = fmaf(rv.x, cv0.z, acc[r].z);
            acc[r].w = fmaf(rv.x, cv0.w, acc[r].w);
            acc[r].x = fmaf(rv.y, cv1.x, acc[r].x);
            acc[r].y = fmaf(rv.y, cv1.y, acc[r].y);
            acc[r].z = fmaf(rv.y, cv1.z, acc[r].z);
            acc[r].w = fmaf(rv.y, cv1.w, acc[r].w);
            acc[r].x = fmaf(rv.z, cv2.x, acc[r].x);
            acc[r].y = fmaf(rv.z, cv2.y, acc[r].y);
            acc[r].z = fmaf(rv.z, cv2.z, acc[r].z);
            acc[r].w = fmaf(rv.z, cv2.w, acc[r].w);
            acc[r].x = fmaf(rv.w, cv3.x, acc[r].x);
            acc[r].y = fmaf(rv.w, cv3.y, acc[r].y);
            acc[r].z = fmaf(rv.w, cv3.z, acc[r].z);
            acc[r].w = fmaf(rv.w, cv3.w, acc[r].w);
        }
    }
#pragma unroll
    for (int r = 0; r < ROWS; ++r) *(float4*)&sD[r][c0] = acc[r];
    __syncthreads();

    // selection phase: wave w handles rows w and w+4
    for (int rr = 0; rr < 2; ++rr) {
        int r = w + rr * 4;
        int n = n0 + r;
        if (n >= cnt) continue;                     // wave-uniform
        float x2n = sX2[n];
        unsigned long long packed[16];
#pragma unroll
        for (int tt = 0; tt < 16; ++tt) {
            int c = (tt << 6) + lane;
            float dot = sD[r][c];
            float dd = fmaxf((x2n + sX2[c]) - 2.0f * dot, 0.0f);
            packed[tt] = (c < cnt && c != n)
                ? (((unsigned long long)__float_as_uint(dd) << 32) | (unsigned)c)
                : ~0ULL;
        }
        // Batcher odd-even mergesort, 16 elements, ascending (63 CEs)
        CE(0,1) CE(2,3) CE(4,5) CE(6,7) CE(8,9) CE(10,11) CE(12,13) CE(14,15)
        CE(0,2) CE(1,3) CE(4,6) CE(5,7) CE(8,10) CE(9,11) CE(12,14) CE(13,15)
        CE(1,2) CE(5,6) CE(9,10) CE(13,14)
        CE(0,4) CE(1,5) CE(2,6) CE(3,7) CE(8,12) CE(9,13) CE(10,14) CE(11,15)
        CE(2,4) CE(3,5) CE(10,12) CE(11,13)
        CE(1,2) CE(3,4) CE(5,6) CE(9,10) CE(11,12) CE(13,14)
        CE(0,8) CE(1,9) CE(2,10) CE(3,11) CE(4,12) CE(5,13) CE(6,14) CE(7,15)
        CE(4,8) CE(5,9) CE(6,10) CE(7,11)
        CE(2,4) CE(3,5) CE(6,8) CE(7,9) CE(10,12) CE(11,13)
        CE(1,2) CE(3,4) CE(5,6) CE(7,8) CE(9,10) CE(11,12) CE(13,14)

        unsigned long long myhead = packed[0];
        int my_m = 0;
        for (int j = 0; j < kef; ++j) {
            unsigned long long g = myhead;
            for (int off = 32; off; off >>= 1) {
                unsigned long long o = __shfl_xor(g, off);
                g = (o < g) ? o : g;
            }
            my_m = (j == lane) ? (int)(unsigned)(g & 0xffffffffu) : my_m;
            bool win = (myhead == g);               // unique (index bits distinct)
#pragma unroll
            for (int tt = 0; tt < 15; ++tt) packed[tt] = win ? packed[tt + 1] : packed[tt];
            packed[15] = win ? ~0ULL : packed[15];
            myhead = packed[0];
        }
        if (lane < KMAX) {
            size_t p = (size_t)(b << 10) + n;
            idx[p * KMAX + lane] = (lane < kef) ? my_m : 0;
        }
    }
}

// ---------------- K3: gather + GN + ReLU + W2 + maxpool (pipelined) ----------------
__global__ __launch_bounds__(256) void k3_mlp(const float* __restrict__ base,
                                              const float* __restrict__ fb,
                                              const int* __restrict__ idx,
                                              const int* __restrict__ counts,
                                              const float* __restrict__ gamma,
                                              const float* __restrict__ beta,
                                              const float* __restrict__ W2,
                                              const float* __restrict__ b2,
                                              float* __restrict__ out) {
    __shared__ float sH[4][CC];
    int w = threadIdx.x >> 6, lane = threadIdx.x & 63;
    int p = blockIdx.x * 4 + w;
    int b = p >> 10, n = p & 1023;
    bool valid = n < counts[b];                     // wave-uniform
    if (!valid) { out[(size_t)p * CC + lane] = 0.0f; return; }
    float w2c[CC];                                  // W2 column `lane` in VGPRs
#pragma unroll
    for (int c = 0; c < CC; ++c) w2c[c] = W2[(c << 6) + lane];
    float basec = base[(size_t)p * CC + lane];
    float g = gamma[lane], be = beta[lane], b2c = b2[lane];
    const float* fbb = fb + ((size_t)(b << 10)) * CC;
    const int* idxp = idx + (size_t)p * KMAX;
    float acc = -1e30f;
    int m0 = idxp[0];
    float hload = fbb[((size_t)m0 << 6) + lane];
#pragma unroll
    for (int j = 0; j < KMAX; ++j) {
        int mn = (j + 1 < KMAX) ? idxp[j + 1] : 0;
        float hnext = fbb[((size_t)mn << 6) + lane];   // issued early, hides latency
        float h = basec + hload;
        float s = h + __shfl_xor(h, 1);
        s += __shfl_xor(s, 2);
        float mu = s * 0.25f;
        float d = h - mu;
        float q = d * d;
        float qs = q + __shfl_xor(q, 1);
        qs += __shfl_xor(qs, 2);
        float var = qs * 0.25f;
        float hn = d * __builtin_amdgcn_rsqf(var + 1e-5f) * g + be;
        hn = fmaxf(hn, 0.0f);
        sH[w][lane] = hn;                            // same-wave LDS: in-order, no barrier
        float a2 = b2c;
        const float4* sh4 = (const float4*)(&sH[w][0]);
#pragma unroll
        for (int qq = 0; qq < 16; ++qq) {
            float4 hv = sh4[qq];                     // wave-uniform broadcast b128
            a2 = fmaf(hv.x, w2c[4 * qq + 0], a2);
            a2 = fmaf(hv.y, w2c[4 * qq + 1], a2);
            a2 = fmaf(hv.z, w2c[4 * qq + 2], a2);
            a2 = fmaf(hv.w, w2c[4 * qq + 3], a2);
        }
        acc = fmaxf(acc, a2);
        hload = hnext;
    }
    out[(size_t)p * CC + lane] = acc;
}

extern "C" void kernel_launch(void* const* d_in, const int* in_sizes, int n_in,
                              void* d_out, int out_size, void* d_ws, size_t ws_size,
                              hipStream_t stream) {
    const float* x     = (const float*)d_in[0];
    const void*  maskp = d_in[1];
    const float* W1    = (const float*)d_in[2];
    const float* b1    = (const float*)d_in[3];
    const float* gamma = (const float*)d_in[4];
    const float* beta  = (const float*)d_in[5];
    const float* W2    = (const float*)d_in[6];
    const float* b2    = (const float*)d_in[7];
    float* out = (float*)d_out;

    int* d_counts = (int*)d_ws;
    int* d_keff   = d_counts + 16;
    float* d_x2   = (float*)(d_counts + 32);
    float* d_base = d_x2 + BB * NN;
    float* d_fb   = d_base + (size_t)BB * NN * CC;
    int* d_idx    = (int*)(d_fb + (size_t)BB * NN * CC);
    float* d_xT   = (float*)d_out;   // free until k3

    hipLaunchKernelGGL(k0_counts, dim3(1), dim3(1024), 0, stream, maskp, d_counts, d_keff);
    hipLaunchKernelGGL(k1_feats, dim3(BB * NN / 4), dim3(256), 0, stream,
                       x, W1, b1, d_base, d_fb, d_x2, d_xT);
    hipLaunchKernelGGL(k2_knn, dim3(BB * (NN / ROWS)), dim3(256), 0, stream,
                       x, d_xT, d_x2, d_counts, d_keff, d_idx);
    hipLaunchKernelGGL(k3_mlp, dim3(BB * NN / 4), dim3(256), 0, stream,
                       d_base, d_fb, d_idx, d_counts, gamma, beta, W2, b2, out);
}

// Round 4
// 131.262 us; speedup vs baseline: 1.5700x; 1.5700x over previous
//
#include <hip/hip_runtime.h>
#include <stdint.h>

#define BB 16
#define NN 1024
#define DD 64
#define CC 64
#define KMAX 20
#define ROWS 4

typedef unsigned long long u64;

__device__ inline u64 umin64(u64 a, u64 b) { return a < b ? a : b; }

// full ascending bitonic sort of one u64 per lane across 64 lanes
__device__ inline u64 bitonic_sort64(u64 v, int lane) {
#pragma unroll
    for (int k = 2; k <= 64; k <<= 1) {
#pragma unroll
        for (int j = k >> 1; j > 0; j >>= 1) {
            u64 o = __shfl_xor(v, j);
            bool keepmin = (((lane & j) == 0) == ((lane & k) == 0));
            bool take = ((o < v) == keepmin);
            v = take ? o : v;
        }
    }
    return v;
}

// ---------------- K0: counts + k_eff (one block) ----------------
__global__ void k0_counts(const void* __restrict__ maskp,
                          int* __restrict__ counts, int* __restrict__ keff) {
    __shared__ int scnt[BB];
    int tid = threadIdx.x;
    int w = tid >> 6, lane = tid & 63;
    const unsigned char* mb = (const unsigned char*)maskp;
    const int* mi = (const int*)maskp;
    bool bytelayout = (mb[1] != 0);
    int s = 0;
    for (int i = 0; i < 16; ++i) {
        int n = lane + (i << 6);
        int v = bytelayout ? (mb[w * NN + n] ? 1 : 0) : (mi[w * NN + n] ? 1 : 0);
        s += v;
    }
    for (int off = 32; off; off >>= 1) s += __shfl_xor(s, off);
    if (lane == 0) scnt[w] = s;
    __syncthreads();
    if (tid < BB) {
        int minc = scnt[0];
        for (int q = 1; q < BB; ++q) minc = min(minc, scnt[q]);
        int kglob = min(KMAX, max(1, minc - 1));
        float c = (float)scnt[tid];
        float v = sqrtf(c / 50.0f) * 8.0f;
        v = fminf(fmaxf(v, 8.0f), 20.0f);
        int kper = (int)v;
        counts[tid] = scnt[tid];
        keff[tid] = min(kper, kglob);
    }
}

// ---------------- K1: base/fb feats + x2 + transpose x -> xT[b][d][n] ----------------
__global__ void k1_feats(const float* __restrict__ x, const float* __restrict__ W1,
                         const float* __restrict__ b1, float* __restrict__ base,
                         float* __restrict__ fb, float* __restrict__ x2,
                         float* __restrict__ xT) {
    __shared__ float sXT[DD][4];
    int w = threadIdx.x >> 6, lane = threadIdx.x & 63;
    int p = blockIdx.x * 4 + w;
    const float* xp = x + (size_t)p * DD;
    float xv = xp[lane];
    float sq = xv * xv;
    for (int off = 32; off; off >>= 1) sq += __shfl_xor(sq, off);
    if (lane == 0) x2[p] = sq;
    sXT[lane][w] = xv;
    float acc_a = 0.f, acc_b = 0.f;
#pragma unroll
    for (int d = 0; d < DD; ++d) {
        float xd = __shfl(xv, d);  // == xp[d], bit-identical
        acc_a = fmaf(xd, W1[d * CC + lane], acc_a);
        acc_b = fmaf(xd, W1[(DD + d) * CC + lane], acc_b);
    }
    base[(size_t)p * CC + lane] = acc_a - acc_b + b1[lane];
    fb[(size_t)p * CC + lane] = acc_b;
    __syncthreads();
    int t = threadIdx.x;
    int d = t >> 2, po = t & 3;
    int p0 = blockIdx.x * 4;
    int b = p0 >> 10, nb = p0 & 1023;
    xT[(((size_t)(b << 6) + d) << 10) + nb + po] = sXT[d][po];
}

// Batcher odd-even mergesort compare-exchange (ascending) — fallback path
#define CE(a, b)                                                      \
    {                                                                 \
        bool sw_ = pk[b] < pk[a];                                     \
        u64 ta_ = pk[a];                                              \
        pk[a] = sw_ ? pk[b] : pk[a];                                  \
        pk[b] = sw_ ? ta_ : pk[b];                                    \
    }

// ---------------- K2: GEMM-style dist + threshold/compact/bitonic top-k ----------------
__global__ __launch_bounds__(256) void k2_knn(const float* __restrict__ x,
                                              const float* __restrict__ xT,
                                              const float* __restrict__ x2,
                                              const int* __restrict__ counts,
                                              const int* __restrict__ keff,
                                              int* __restrict__ idx) {
    __shared__ float sD[ROWS][NN];
    __shared__ float sRow[ROWS][DD];
    __shared__ float sX2[NN];
    __shared__ u64 sSv[ROWS][64];
    int b = blockIdx.x >> 8;
    int n0 = (blockIdx.x & 255) * ROWS;
    int w = threadIdx.x >> 6, lane = threadIdx.x & 63;
    int cnt = counts[b], kef = keff[b];
    int t = threadIdx.x;
    if (t < ROWS * 16) {
        int r = t >> 4, dc = (t & 15) << 2;
        *(float4*)&sRow[r][dc] =
            *(const float4*)(x + ((size_t)(b << 10) + n0 + r) * DD + dc);
    }
    *(float4*)&sX2[t << 2] = *(const float4*)(x2 + (b << 10) + (t << 2));
    __syncthreads();

    // GEMM phase: wave w covers candidates c0 = w*256 + lane*4 .. +3, all 4 rows
    float4 acc[ROWS];
#pragma unroll
    for (int r = 0; r < ROWS; ++r) acc[r] = make_float4(0.f, 0.f, 0.f, 0.f);
    const float* xTb = xT + ((size_t)b << 16);
    int c0 = (w << 8) + (lane << 2);
    for (int d0 = 0; d0 < DD; d0 += 4) {
        float4 cv0 = *(const float4*)(xTb + ((size_t)(d0 + 0) << 10) + c0);
        float4 cv1 = *(const float4*)(xTb + ((size_t)(d0 + 1) << 10) + c0);
        float4 cv2 = *(const float4*)(xTb + ((size_t)(d0 + 2) << 10) + c0);
        float4 cv3 = *(const float4*)(xTb + ((size_t)(d0 + 3) << 10) + c0);
#pragma unroll
        for (int r = 0; r < ROWS; ++r) {
            float4 rv = *(const float4*)(&sRow[r][d0]);   // wave-uniform broadcast
            acc[r].x = fmaf(rv.x, cv0.x, acc[r].x);
            acc[r].y = fmaf(rv.x, cv0.y, acc[r].y);
            acc[r].z = fmaf(rv.x, cv0.z, acc[r].z);
            acc[r].w = fmaf(rv.x, cv0.w, acc[r].w);
            acc[r].x = fmaf(rv.y, cv1.x, acc[r].x);
            acc[r].y = fmaf(rv.y, cv1.y, acc[r].y);
            acc[r].z = fmaf(rv.y, cv1.z, acc[r].z);
            acc[r].w = fmaf(rv.y, cv1.w, acc[r].w);
            acc[r].x = fmaf(rv.z, cv2.x, acc[r].x);
            acc[r].y = fmaf(rv.z, cv2.y, acc[r].y);
            acc[r].z = fmaf(rv.z, cv2.z, acc[r].z);
            acc[r].w = fmaf(rv.z, cv2.w, acc[r].w);
            acc[r].x = fmaf(rv.w, cv3.x, acc[r].x);
            acc[r].y = fmaf(rv.w, cv3.y, acc[r].y);
            acc[r].z = fmaf(rv.w, cv3.z, acc[r].z);
            acc[r].w = fmaf(rv.w, cv3.w, acc[r].w);
        }
    }
#pragma unroll
    for (int r = 0; r < ROWS; ++r) *(float4*)&sD[r][c0] = acc[r];
    __syncthreads();

    // selection: wave w owns row w
    int r = w;
    int n = n0 + r;
    if (n >= cnt) return;                           // wave-uniform
    float x2n = sX2[n];
    u64 pk[16];
#pragma unroll
    for (int tt = 0; tt < 16; ++tt) {
        int c = (tt << 6) + lane;
        float dot = sD[r][c];
        float dd = fmaxf((x2n + sX2[c]) - 2.0f * dot, 0.0f);
        pk[tt] = (c < cnt && c != n)
            ? (((u64)__float_as_uint(dd) << 32) | (unsigned)c)
            : ~0ULL;
    }
    // lane-min tree (head)
    u64 h01 = umin64(pk[0], pk[1]),   h23 = umin64(pk[2], pk[3]);
    u64 h45 = umin64(pk[4], pk[5]),   h67 = umin64(pk[6], pk[7]);
    u64 h89 = umin64(pk[8], pk[9]),   hab = umin64(pk[10], pk[11]);
    u64 hcd = umin64(pk[12], pk[13]), hef = umin64(pk[14], pk[15]);
    u64 h = umin64(umin64(umin64(h01, h23), umin64(h45, h67)),
                   umin64(umin64(h89, hab), umin64(hcd, hef)));
    // threshold = kef-th smallest head (>= true kef-th smallest overall)
    u64 hs = bitonic_sort64(h, lane);
    u64 t0 = __shfl(hs, kef - 1);
    // count survivors per lane + exclusive scan
    int cle = 0;
#pragma unroll
    for (int i = 0; i < 16; ++i) cle += (pk[i] <= t0) ? 1 : 0;
    int incl = cle;
#pragma unroll
    for (int off = 1; off < 64; off <<= 1) {
        int o = __shfl_up(incl, off);
        incl += (lane >= off) ? o : 0;
    }
    int S = __shfl(incl, 63);
    size_t prow = (size_t)(b << 10) + n;
    if (S <= 64) {
        // compact survivors to LDS, one bitonic sort, done
        int pos = incl - cle;
#pragma unroll
        for (int i = 0; i < 16; ++i) {
            if (pk[i] <= t0) { sSv[w][pos] = pk[i]; ++pos; }
        }
        u64 sv = (lane < S) ? sSv[w][lane] : ~0ULL;   // same-wave LDS, compiler-ordered
        sv = bitonic_sort64(sv, lane);
        if (lane < KMAX)
            idx[prow * KMAX + lane] = (lane < kef) ? (int)(unsigned)(sv & 0xffffffffu) : 0;
    } else {
        // exact fallback: Batcher sort + pop (provably identical order)
        CE(0,1) CE(2,3) CE(4,5) CE(6,7) CE(8,9) CE(10,11) CE(12,13) CE(14,15)
        CE(0,2) CE(1,3) CE(4,6) CE(5,7) CE(8,10) CE(9,11) CE(12,14) CE(13,15)
        CE(1,2) CE(5,6) CE(9,10) CE(13,14)
        CE(0,4) CE(1,5) CE(2,6) CE(3,7) CE(8,12) CE(9,13) CE(10,14) CE(11,15)
        CE(2,4) CE(3,5) CE(10,12) CE(11,13)
        CE(1,2) CE(3,4) CE(5,6) CE(9,10) CE(11,12) CE(13,14)
        CE(0,8) CE(1,9) CE(2,10) CE(3,11) CE(4,12) CE(5,13) CE(6,14) CE(7,15)
        CE(4,8) CE(5,9) CE(6,10) CE(7,11)
        CE(2,4) CE(3,5) CE(6,8) CE(7,9) CE(10,12) CE(11,13)
        CE(1,2) CE(3,4) CE(5,6) CE(7,8) CE(9,10) CE(11,12) CE(13,14)
        u64 myhead = pk[0];
        int my_m = 0;
        for (int j = 0; j < kef; ++j) {
            u64 g = myhead;
            for (int off = 32; off; off >>= 1) {
                u64 o = __shfl_xor(g, off);
                g = (o < g) ? o : g;
            }
            my_m = (j == lane) ? (int)(unsigned)(g & 0xffffffffu) : my_m;
            bool win = (myhead == g);
#pragma unroll
            for (int tt = 0; tt < 15; ++tt) pk[tt] = win ? pk[tt + 1] : pk[tt];
            pk[15] = win ? ~0ULL : pk[15];
            myhead = pk[0];
        }
        if (lane < KMAX)
            idx[prow * KMAX + lane] = (lane < kef) ? my_m : 0;
    }
}

// ---------------- K3: gather + GN + ReLU + W2 + maxpool (pipelined) ----------------
__global__ __launch_bounds__(256) void k3_mlp(const float* __restrict__ base,
                                              const float* __restrict__ fb,
                                              const int* __restrict__ idx,
                                              const int* __restrict__ counts,
                                              const float* __restrict__ gamma,
                                              const float* __restrict__ beta,
                                              const float* __restrict__ W2,
                                              const float* __restrict__ b2,
                                              float* __restrict__ out) {
    __shared__ float sH[4][CC];
    int w = threadIdx.x >> 6, lane = threadIdx.x & 63;
    int p = blockIdx.x * 4 + w;
    int b = p >> 10, n = p & 1023;
    bool valid = n < counts[b];                     // wave-uniform
    if (!valid) { out[(size_t)p * CC + lane] = 0.0f; return; }
    float w2c[CC];                                  // W2 column `lane` in VGPRs
#pragma unroll
    for (int c = 0; c < CC; ++c) w2c[c] = W2[(c << 6) + lane];
    float basec = base[(size_t)p * CC + lane];
    float g = gamma[lane], be = beta[lane], b2c = b2[lane];
    const float* fbb = fb + ((size_t)(b << 10)) * CC;
    const int* idxp = idx + (size_t)p * KMAX;
    float acc = -1e30f;
    int m0 = idxp[0];
    float hload = fbb[((size_t)m0 << 6) + lane];
#pragma unroll
    for (int j = 0; j < KMAX; ++j) {
        int mn = (j + 1 < KMAX) ? idxp[j + 1] : 0;
        float hnext = fbb[((size_t)mn << 6) + lane];   // issued early, hides latency
        float h = basec + hload;
        float s = h + __shfl_xor(h, 1);
        s += __shfl_xor(s, 2);
        float mu = s * 0.25f;
        float d = h - mu;
        float q = d * d;
        float qs = q + __shfl_xor(q, 1);
        qs += __shfl_xor(qs, 2);
        float var = qs * 0.25f;
        float hn = d * __builtin_amdgcn_rsqf(var + 1e-5f) * g + be;
        hn = fmaxf(hn, 0.0f);
        sH[w][lane] = hn;                            // same-wave LDS: in-order
        float a2 = b2c;
        const float4* sh4 = (const float4*)(&sH[w][0]);
#pragma unroll
        for (int qq = 0; qq < 16; ++qq) {
            float4 hv = sh4[qq];                     // wave-uniform broadcast b128
            a2 = fmaf(hv.x, w2c[4 * qq + 0], a2);
            a2 = fmaf(hv.y, w2c[4 * qq + 1], a2);
            a2 = fmaf(hv.z, w2c[4 * qq + 2], a2);
            a2 = fmaf(hv.w, w2c[4 * qq + 3], a2);
        }
        acc = fmaxf(acc, a2);
        hload = hnext;
    }
    out[(size_t)p * CC + lane] = acc;
}

extern "C" void kernel_launch(void* const* d_in, const int* in_sizes, int n_in,
                              void* d_out, int out_size, void* d_ws, size_t ws_size,
                              hipStream_t stream) {
    const float* x     = (const float*)d_in[0];
    const void*  maskp = d_in[1];
    const float* W1    = (const float*)d_in[2];
    const float* b1    = (const float*)d_in[3];
    const float* gamma = (const float*)d_in[4];
    const float* beta  = (const float*)d_in[5];
    const float* W2    = (const float*)d_in[6];
    const float* b2    = (const float*)d_in[7];
    float* out = (float*)d_out;

    int* d_counts = (int*)d_ws;
    int* d_keff   = d_counts + 16;
    float* d_x2   = (float*)(d_counts + 32);
    float* d_base = d_x2 + BB * NN;
    float* d_fb   = d_base + (size_t)BB * NN * CC;
    int* d_idx    = (int*)(d_fb + (size_t)BB * NN * CC);
    float* d_xT   = (float*)d_out;   // free until k3

    hipLaunchKernelGGL(k0_counts, dim3(1), dim3(1024), 0, stream, maskp, d_counts, d_keff);
    hipLaunchKernelGGL(k1_feats, dim3(BB * NN / 4), dim3(256), 0, stream,
                       x, W1, b1, d_base, d_fb, d_x2, d_xT);
    hipLaunchKernelGGL(k2_knn, dim3(BB * (NN / ROWS)), dim3(256), 0, stream,
                       x, d_xT, d_x2, d_counts, d_keff, d_idx);
    hipLaunchKernelGGL(k3_mlp, dim3(BB * NN / 4), dim3(256), 0, stream,
                       d_base, d_fb, d_idx, d_counts, gamma, beta, W2, b2, out);
}